// Round 4
// baseline (1968.964 us; speedup 1.0000x reference)
//
#include <hip/hip_runtime.h>

// LSTM char-RNN forward: batch=1024, T=512, UNITS=256, NUM_CHARS=128.
// R12: two-phase interleaved recurrences. 256 blocks x 512 threads.
// Block bid = gp*8+s owns unit-slice s (32 units) of TWO groups: gA=2*gp
// (computed in phase A) and gB=2*gp+1 (phase B). Phases alternate within
// each step; a group's h (published end of its phase) is consumed at the
// same phase of the next iteration, so the agent-scope exchange round trip
// (~900cyc, structural per R9/R10) is hidden under the OTHER group's full
// phase (~1000cyc of MFMA+gates). Polls are pre-issued mid-previous-phase
// and register-pinned so even poll-issue latency is off the critical path.
// Both tasks use the same unit-slice -> one shared set of 8 Wh B-frags.
// Exchange keeps the proven u64 (tag32|2xfp16) parity-double-buffered
// agent-scope scheme (stale/poison/replay-proof via tag==t equality).
// Same gate math/b-frag/a-frag/C layouts as R11 -> absmax ~6e-5.

#define TSTEPS 512
#define UNITS  256
#define NCHAR  128
#define G4     1024
#define ZSB    132   // zbuf row stride (128 cols + pad)

typedef float    f32x4 __attribute__((ext_vector_type(4)));
typedef _Float16 f16x8 __attribute__((ext_vector_type(8)));

union FU { uint4 u4; f16x8 h8; _Float16 h[8]; };
union HP { unsigned int u; _Float16 f[2]; };

__device__ __forceinline__ float fast_rcp(float x) {
#if __has_builtin(__builtin_amdgcn_rcpf)
  return __builtin_amdgcn_rcpf(x);
#else
  return 1.0f / x;
#endif
}
__device__ __forceinline__ float sigm(float x)  { return fast_rcp(1.0f + __expf(-x)); }
__device__ __forceinline__ float tanhx(float x) { return 2.0f * fast_rcp(1.0f + __expf(-2.0f * x)) - 1.0f; }

// ---- Prep: WhB = Wh fp16 B-fragment stream. idx=(nt*8+kk)*64+l, nt=cc*32+tile.
__global__ void prep_whB(const float* __restrict__ Wh, uint4* __restrict__ WhB) {
  int idx = blockIdx.x * blockDim.x + threadIdx.x;    // 0..32767
  int l    = idx & 63;
  int kk   = (idx >> 6) & 7;
  int tile = (idx >> 9) & 31;
  int cc   = idx >> 14;
  int n    = tile * 16 + (l & 15);
  int gate = n & 3;
  int col  = gate * 256 + cc * 128 + (n >> 2);
  int kb   = kk * 32 + (l >> 4) * 8;
  FU p;
#pragma unroll
  for (int j = 0; j < 8; ++j)
    p.h[j] = (_Float16)Wh[(kb + j) * G4 + col];
  WhB[idx] = p.u4;
}

// ---- Prep: Wxbg[ch][u] = float4(i,f,g,o) = Wx[ch][gate*256+u] + b
__global__ void prep_wx(const float* __restrict__ Wx, const float* __restrict__ bias,
                        float4* __restrict__ Wxbg) {
  int idx = blockIdx.x * blockDim.x + threadIdx.x;    // 0..32767
  int u  = idx & (UNITS - 1);
  int ch = idx >> 8;
  const float* r = Wx + ch * G4;
  float4 o;
  o.x = r[0 * UNITS + u] + bias[0 * UNITS + u];
  o.y = r[1 * UNITS + u] + bias[1 * UNITS + u];
  o.z = r[2 * UNITS + u] + bias[2 * UNITS + u];
  o.w = r[3 * UNITS + u] + bias[3 * UNITS + u];
  Wxbg[idx] = o;
}

// A-frag LDS byte address for h element (row m, k). Proven layout (R8/R11).
__device__ __forceinline__ int afrag_addr(int k, int m) {
  return ((k >> 5) << 10) + (((((k >> 3) & 3) << 4) + m) << 4) + ((k & 7) << 1);
}

#define SPJ(j) ((j) + ((j) >= s ? 1 : 0))

// ---- Main: 256 blocks x 512 threads.
__global__ __launch_bounds__(512) void lstm_mfma(
    const int* __restrict__ inp, const uint4* __restrict__ WhB,
    const float4* __restrict__ Wxbg, const float* __restrict__ Wd,
    const float* __restrict__ bd, float* __restrict__ out,
    unsigned long long* __restrict__ hx) {
  // [0..511] = group-A A-frags, [512..1023] = group-B. Epilogue overlays
  // the same 16KB as hT: fp32 [16][256].
  __shared__ __align__(16) uint4 hfrag2[1024];
  __shared__ float zbuf[16 * ZSB];               // shared by both phases
  __shared__ float lgts[16 * 132];
  __shared__ float rmax[16], rsum[16];

  const int tid  = threadIdx.x;
  const int lane = tid & 63;
  const int wv   = tid >> 6;          // 0..7 = wave = col-tile
  const int bid  = blockIdx.x;
  const int gp   = bid >> 3;          // group pair 0..31
  const int s    = bid & 7;           // unit slice 0..7
  const int gA   = gp * 2, gB = gp * 2 + 1;
  const int r    = tid >> 5;          // 0..15 batch row within group
  const int uis  = tid & 31;          // unit within slice
  const int ubase = s * 32;
  const int NT   = (s >> 2) * 32 + (s & 3) * 8;  // first global col-tile of slice
  const int cq   = lane >> 4, cn = lane & 15;

  // pollers: even threads, word index q in [0,256)
  const bool poller = (tid & 1) == 0;
  const int q   = tid >> 1;
  const int rq  = q >> 4;
  const int up0 = (q & 15) * 2;

  // partner word offsets and A-frag byte addrs (7 partner slices)
  const int wo0 = SPJ(0) * 256 + q, wo1 = SPJ(1) * 256 + q, wo2 = SPJ(2) * 256 + q,
            wo3 = SPJ(3) * 256 + q, wo4 = SPJ(4) * 256 + q, wo5 = SPJ(5) * 256 + q,
            wo6 = SPJ(6) * 256 + q;
  const int a0 = afrag_addr(SPJ(0) * 32 + up0, rq), a1 = afrag_addr(SPJ(1) * 32 + up0, rq),
            a2 = afrag_addr(SPJ(2) * 32 + up0, rq), a3 = afrag_addr(SPJ(3) * 32 + up0, rq),
            a4 = afrag_addr(SPJ(4) * 32 + up0, rq), a5 = afrag_addr(SPJ(5) * 32 + up0, rq),
            a6 = afrag_addr(SPJ(6) * 32 + up0, rq);
  const int aown = afrag_addr(ubase + uis, r);    // even threads: 4-aligned u32 slot

  // ---- shared weight B-frags (same slice -> same weights for both groups)
  FU wf[8];
#pragma unroll
  for (int kk = 0; kk < 8; ++kk)
    wf[kk].u4 = WhB[((NT + wv) * 8 + kk) * 64 + lane];
#pragma unroll
  for (int kk = 0; kk < 8; ++kk)
    asm volatile("" : "+v"(wf[kk].u4.x), "+v"(wf[kk].u4.y), "+v"(wf[kk].u4.z), "+v"(wf[kk].u4.w));

  hfrag2[tid]       = uint4{0u, 0u, 0u, 0u};     // h_0 = 0 (both groups)
  hfrag2[tid + 512] = uint4{0u, 0u, 0u, 0u};
  float cstA = 0.f, cstB = 0.f;
  unsigned lastA = 0, lastB = 0;
  unsigned long long p0 = 0, p1 = 0, p2 = 0, p3 = 0, p4 = 0, p5 = 0, p6 = 0;
  __syncthreads();

  for (int ph = 0; ph < 2 * TSTEPS; ++ph) {
    const int t   = ph >> 1;
    const int isB = ph & 1;
    const int g   = isB ? gB : gA;
    uint4* hf     = hfrag2 + (isB << 9);

    int    chx = inp[(g * 16 + r) * TSTEPS + t];
    float4 xb  = Wxbg[chx * 256 + ubase + uis];

    // ---- gather: pre-issued polls (from mid-previous-phase) checked here;
    // re-poll only if a partner is late. Tag==t equality is the proof.
    if (t > 0 && poller) {
      const unsigned tu = (unsigned)t;
      const unsigned long long* base = hx + (((t & 1) * 64 + g) << 11);
      long guard = 0;
      while (((((unsigned)(p0 >> 32)) ^ tu) | (((unsigned)(p1 >> 32)) ^ tu) |
              (((unsigned)(p2 >> 32)) ^ tu) | (((unsigned)(p3 >> 32)) ^ tu) |
              (((unsigned)(p4 >> 32)) ^ tu) | (((unsigned)(p5 >> 32)) ^ tu) |
              (((unsigned)(p6 >> 32)) ^ tu)) != 0u) {
        if (++guard >= (1L << 14)) break;
        p0 = __hip_atomic_load(base + wo0, __ATOMIC_RELAXED, __HIP_MEMORY_SCOPE_AGENT);
        p1 = __hip_atomic_load(base + wo1, __ATOMIC_RELAXED, __HIP_MEMORY_SCOPE_AGENT);
        p2 = __hip_atomic_load(base + wo2, __ATOMIC_RELAXED, __HIP_MEMORY_SCOPE_AGENT);
        p3 = __hip_atomic_load(base + wo3, __ATOMIC_RELAXED, __HIP_MEMORY_SCOPE_AGENT);
        p4 = __hip_atomic_load(base + wo4, __ATOMIC_RELAXED, __HIP_MEMORY_SCOPE_AGENT);
        p5 = __hip_atomic_load(base + wo5, __ATOMIC_RELAXED, __HIP_MEMORY_SCOPE_AGENT);
        p6 = __hip_atomic_load(base + wo6, __ATOMIC_RELAXED, __HIP_MEMORY_SCOPE_AGENT);
      }
      *(unsigned*)((char*)hf + a0) = (unsigned)p0;
      *(unsigned*)((char*)hf + a1) = (unsigned)p1;
      *(unsigned*)((char*)hf + a2) = (unsigned)p2;
      *(unsigned*)((char*)hf + a3) = (unsigned)p3;
      *(unsigned*)((char*)hf + a4) = (unsigned)p4;
      *(unsigned*)((char*)hf + a5) = (unsigned)p5;
      *(unsigned*)((char*)hf + a6) = (unsigned)p6;
    }
    __syncthreads();   // hfrag complete; also the zbuf handoff barrier

    // ---- MFMA: wave = col-tile NT+wv, all 8 K-chunks
    f32x4 acc = {0.f, 0.f, 0.f, 0.f};
#pragma unroll
    for (int kk = 0; kk < 8; ++kk) {
      FU a; a.u4 = hf[kk * 64 + lane];
      acc = __builtin_amdgcn_mfma_f32_16x16x32_f16(a.h8, wf[kk].h8, acc, 0, 0, 0);
    }
#pragma unroll
    for (int reg = 0; reg < 4; ++reg)
      zbuf[(cq * 4 + reg) * ZSB + wv * 16 + cn] = acc[reg];
    __syncthreads();   // zbuf ready

    // ---- pre-issue polls for the NEXT phase (its publishes happened >=1
    // phase ago; the check happens ~a gates-length later). Register-pinned
    // so the compiler can't sink the loads to the use point.
    {
      const int tn = (ph + 1) >> 1;
      if (poller && tn >= 1 && ph + 1 < 2 * TSTEPS) {
        const int gn = isB ? gA : gB;
        const unsigned long long* nb2 = hx + (((tn & 1) * 64 + gn) << 11);
        p0 = __hip_atomic_load(nb2 + wo0, __ATOMIC_RELAXED, __HIP_MEMORY_SCOPE_AGENT);
        p1 = __hip_atomic_load(nb2 + wo1, __ATOMIC_RELAXED, __HIP_MEMORY_SCOPE_AGENT);
        p2 = __hip_atomic_load(nb2 + wo2, __ATOMIC_RELAXED, __HIP_MEMORY_SCOPE_AGENT);
        p3 = __hip_atomic_load(nb2 + wo3, __ATOMIC_RELAXED, __HIP_MEMORY_SCOPE_AGENT);
        p4 = __hip_atomic_load(nb2 + wo4, __ATOMIC_RELAXED, __HIP_MEMORY_SCOPE_AGENT);
        p5 = __hip_atomic_load(nb2 + wo5, __ATOMIC_RELAXED, __HIP_MEMORY_SCOPE_AGENT);
        p6 = __hip_atomic_load(nb2 + wo6, __ATOMIC_RELAXED, __HIP_MEMORY_SCOPE_AGENT);
        asm volatile("" : "+v"(p0), "+v"(p1), "+v"(p2), "+v"(p3), "+v"(p4), "+v"(p5), "+v"(p6));
      }
    }

    // ---- gates: thread = (row r, unit ubase+uis)
    {
      float4 z = *(const float4*)&zbuf[r * ZSB + uis * 4];
      float i0 = sigm(z.x + xb.x), f0 = sigm(z.y + xb.y);
      float g0 = tanhx(z.z + xb.z), o0 = sigm(z.w + xb.w);
      float cs = isB ? cstB : cstA;
      cs = f0 * cs + i0 * g0;
      float h = o0 * tanhx(cs);
      if (isB) cstB = cs; else cstA = cs;
      HP pk; pk.u = 0; pk.f[0] = (_Float16)h;
      unsigned hb = pk.u & 0xffffu;
      if (isB) lastB = hb; else lastA = hb;
      unsigned nb = (unsigned)__shfl_down((int)hb, 1, 64);
      if (poller) {   // even threads publish the (uis, uis+1) pair
        unsigned pay = hb | (nb << 16);
        *(unsigned*)((char*)hf + aown) = pay;   // own pair into A-frags
        unsigned long long val =
            ((unsigned long long)(unsigned)(t + 1) << 32) | (unsigned long long)pay;
        __hip_atomic_store(hx + ((((t + 1) & 1) * 64 + g) << 11) + s * 256 + q, val,
                           __ATOMIC_RELAXED, __HIP_MEMORY_SCOPE_AGENT);
      }
    }
    // no trailing barrier: the next phase's gather barrier separates
    // zbuf reads (here) from the next zbuf writes, and own-pair hfrag
    // stores from the next same-parity MFMA reads (>=2 barriers away).
  }

  if (s != 0) return;

  // ---- Epilogue (slice-0 blocks): both groups, sequentially.
  // hT overlays hfrag2 (16KB = fp32[16][256]). h is the fp16-rounded
  // exchange payload everywhere (same as R8/R11). Final tag = TSTEPS, par 0.
  float* hT = (float*)hfrag2;
#pragma unroll 1
  for (int gi = 0; gi < 2; ++gi) {
    const int g = gi ? gB : gA;
    __syncthreads();   // stragglers' LDS stores / prev-gi lgts reads done
    { HP p; p.u = gi ? lastB : lastA; hT[r * 256 + uis] = (float)p.f[0]; }
    if (poller) {
      const unsigned long long* base = hx + ((unsigned)g << 11);  // par = 0
      const unsigned tu = (unsigned)TSTEPS;
      long guard = 0;
      do {
        p0 = __hip_atomic_load(base + wo0, __ATOMIC_RELAXED, __HIP_MEMORY_SCOPE_AGENT);
        p1 = __hip_atomic_load(base + wo1, __ATOMIC_RELAXED, __HIP_MEMORY_SCOPE_AGENT);
        p2 = __hip_atomic_load(base + wo2, __ATOMIC_RELAXED, __HIP_MEMORY_SCOPE_AGENT);
        p3 = __hip_atomic_load(base + wo3, __ATOMIC_RELAXED, __HIP_MEMORY_SCOPE_AGENT);
        p4 = __hip_atomic_load(base + wo4, __ATOMIC_RELAXED, __HIP_MEMORY_SCOPE_AGENT);
        p5 = __hip_atomic_load(base + wo5, __ATOMIC_RELAXED, __HIP_MEMORY_SCOPE_AGENT);
        p6 = __hip_atomic_load(base + wo6, __ATOMIC_RELAXED, __HIP_MEMORY_SCOPE_AGENT);
      } while (((((unsigned)(p0 >> 32)) ^ tu) | (((unsigned)(p1 >> 32)) ^ tu) |
                (((unsigned)(p2 >> 32)) ^ tu) | (((unsigned)(p3 >> 32)) ^ tu) |
                (((unsigned)(p4 >> 32)) ^ tu) | (((unsigned)(p5 >> 32)) ^ tu) |
                (((unsigned)(p6 >> 32)) ^ tu)) != 0u && ++guard < (1L << 14));
      HP w;
      w.u = (unsigned)p0; hT[rq * 256 + SPJ(0) * 32 + up0] = (float)w.f[0];
                          hT[rq * 256 + SPJ(0) * 32 + up0 + 1] = (float)w.f[1];
      w.u = (unsigned)p1; hT[rq * 256 + SPJ(1) * 32 + up0] = (float)w.f[0];
                          hT[rq * 256 + SPJ(1) * 32 + up0 + 1] = (float)w.f[1];
      w.u = (unsigned)p2; hT[rq * 256 + SPJ(2) * 32 + up0] = (float)w.f[0];
                          hT[rq * 256 + SPJ(2) * 32 + up0 + 1] = (float)w.f[1];
      w.u = (unsigned)p3; hT[rq * 256 + SPJ(3) * 32 + up0] = (float)w.f[0];
                          hT[rq * 256 + SPJ(3) * 32 + up0 + 1] = (float)w.f[1];
      w.u = (unsigned)p4; hT[rq * 256 + SPJ(4) * 32 + up0] = (float)w.f[0];
                          hT[rq * 256 + SPJ(4) * 32 + up0 + 1] = (float)w.f[1];
      w.u = (unsigned)p5; hT[rq * 256 + SPJ(5) * 32 + up0] = (float)w.f[0];
                          hT[rq * 256 + SPJ(5) * 32 + up0 + 1] = (float)w.f[1];
      w.u = (unsigned)p6; hT[rq * 256 + SPJ(6) * 32 + up0] = (float)w.f[0];
                          hT[rq * 256 + SPJ(6) * 32 + up0 + 1] = (float)w.f[1];
    }
    __syncthreads();
    {
      const int j  = tid & 127;
      const int rb = tid >> 7;          // 0..3 -> rows 4rb..4rb+3
      float l0 = bd[j], l1 = bd[j], l2 = bd[j], l3 = bd[j];
      for (int k = 0; k < 256; ++k) {
        float w = Wd[k * NCHAR + j];
        l0 += hT[(rb * 4 + 0) * 256 + k] * w;
        l1 += hT[(rb * 4 + 1) * 256 + k] * w;
        l2 += hT[(rb * 4 + 2) * 256 + k] * w;
        l3 += hT[(rb * 4 + 3) * 256 + k] * w;
      }
      lgts[(rb * 4 + 0) * 132 + j] = l0;
      lgts[(rb * 4 + 1) * 132 + j] = l1;
      lgts[(rb * 4 + 2) * 132 + j] = l2;
      lgts[(rb * 4 + 3) * 132 + j] = l3;
    }
    __syncthreads();
    if (tid < 16) {
      const int rr = tid;
      float m = -1e30f;
      for (int j = 0; j < NCHAR; ++j) m = fmaxf(m, lgts[rr * 132 + j]);
      float sum = 0.f;
      for (int j = 0; j < NCHAR; ++j) sum += __expf(lgts[rr * 132 + j] - m);
      rmax[rr] = m;
      rsum[rr] = fast_rcp(sum);
    }
    __syncthreads();
    {
      const int j  = tid & 127;
      const int rb = tid >> 7;
#pragma unroll
      for (int ii = 0; ii < 4; ++ii) {
        int rr = rb * 4 + ii;
        out[(g * 16 + rr) * NCHAR + j] = __expf(lgts[rr * 132 + j] - rmax[rr]) * rsum[rr];
      }
    }
  }
}

extern "C" void kernel_launch(void* const* d_in, const int* in_sizes, int n_in,
                              void* d_out, int out_size, void* d_ws, size_t ws_size,
                              hipStream_t stream) {
  const int*   inp = (const int*)d_in[0];
  const float* Wx  = (const float*)d_in[1];
  const float* Wh  = (const float*)d_in[2];
  const float* bia = (const float*)d_in[3];
  const float* Wd  = (const float*)d_in[4];
  const float* bd  = (const float*)d_in[5];

  uint4*              WhB  = (uint4*)d_ws;                          // 512 KB
  float4*             Wxbg = (float4*)((char*)d_ws + (512 << 10));  // 512 KB
  unsigned long long* hx   = (unsigned long long*)((char*)d_ws + (1 << 20)); // 2 MB

  prep_whB<<<128, 256, 0, stream>>>(Wh, WhB);
  prep_wx<<<128, 256, 0, stream>>>(Wx, bia, Wxbg);
  lstm_mfma<<<256, 512, 0, stream>>>(inp, WhB, Wxbg, Wd, bd, (float*)d_out, hx);
}

// Round 5
// 1160.988 us; speedup vs baseline: 1.6959x; 1.6959x over previous
//
#include <hip/hip_runtime.h>

// LSTM char-RNN forward: batch=1024, T=512, UNITS=256, NUM_CHARS=128.
// R13: co-resident anti-phased chains. 512 blocks x 256 threads, 8-way
// unit split (block = 32 units of one group), 2 blocks per CU.
//
// R12 post-mortem: software two-phase multiplexing doubled the per-step
// sync count and its pre-issue slack (<1 phase) was smaller than the
// agent-RT -> constant poll misses (FETCH 268MB->1.84GB), 2.2x regression.
// R13 gets the same overlap from HARDWARE co-residency at zero sync cost:
// R11 ran 1 block/CU, so the CU idled during the gather spin (issue-idle
// ~60% per VALUBusy23+Mfma13). Now each CU hosts slices of TWO different
// groups; while one spins on its partners' tags, the other's MFMA+gates
// fill the pipes (m114: co-scheduling is free). Blocks of groups 32..63
// (the bid+256 co-residents under round-robin placement) take a one-time
// ~2000cyc s_nop stagger so the pair starts anti-phased; chains are
// self-timed with equal step length, so the offset persists. Exchange
// keeps the proven u64 (tag32|2xfp16) parity-double-buffered agent-scope
// scheme (stale/poison/replay-proof via tag==t equality). Same gate math,
// same B/A-frag and C layouts as R11 -> absmax ~6e-5.

#define TSTEPS 512
#define UNITS  256
#define NCHAR  128
#define G4     1024
#define ZSB    132   // zbuf row stride (128 cols + pad)

typedef float    f32x4 __attribute__((ext_vector_type(4)));
typedef _Float16 f16x8 __attribute__((ext_vector_type(8)));
typedef unsigned long long ull;

union FU { uint4 u4; f16x8 h8; _Float16 h[8]; };
union HP { unsigned int u; _Float16 f[2]; };

__device__ __forceinline__ float fast_rcp(float x) {
#if __has_builtin(__builtin_amdgcn_rcpf)
  return __builtin_amdgcn_rcpf(x);
#else
  return 1.0f / x;
#endif
}
__device__ __forceinline__ float sigm(float x)  { return fast_rcp(1.0f + __expf(-x)); }
__device__ __forceinline__ float tanhx(float x) { return 2.0f * fast_rcp(1.0f + __expf(-2.0f * x)) - 1.0f; }

// ---- Prep: WhB = Wh fp16 B-fragment stream. idx=(nt*8+kk)*64+l, nt=cc*32+tile.
__global__ void prep_whB(const float* __restrict__ Wh, uint4* __restrict__ WhB) {
  int idx = blockIdx.x * blockDim.x + threadIdx.x;    // 0..32767
  int l    = idx & 63;
  int kk   = (idx >> 6) & 7;
  int tile = (idx >> 9) & 31;
  int cc   = idx >> 14;
  int n    = tile * 16 + (l & 15);
  int gate = n & 3;
  int col  = gate * 256 + cc * 128 + (n >> 2);
  int kb   = kk * 32 + (l >> 4) * 8;
  FU p;
#pragma unroll
  for (int j = 0; j < 8; ++j)
    p.h[j] = (_Float16)Wh[(kb + j) * G4 + col];
  WhB[idx] = p.u4;
}

// ---- Prep: Wxbg[ch][u] = float4(i,f,g,o) = Wx[ch][gate*256+u] + b
__global__ void prep_wx(const float* __restrict__ Wx, const float* __restrict__ bias,
                        float4* __restrict__ Wxbg) {
  int idx = blockIdx.x * blockDim.x + threadIdx.x;    // 0..32767
  int u  = idx & (UNITS - 1);
  int ch = idx >> 8;
  const float* r = Wx + ch * G4;
  float4 o;
  o.x = r[0 * UNITS + u] + bias[0 * UNITS + u];
  o.y = r[1 * UNITS + u] + bias[1 * UNITS + u];
  o.z = r[2 * UNITS + u] + bias[2 * UNITS + u];
  o.w = r[3 * UNITS + u] + bias[3 * UNITS + u];
  Wxbg[idx] = o;
}

// A-frag LDS byte address for h element (row m, k). Proven layout (R8/R11).
__device__ __forceinline__ int afrag_addr(int k, int m) {
  return ((k >> 5) << 10) + (((((k >> 3) & 3) << 4) + m) << 4) + ((k & 7) << 1);
}

#define SPJ(j) ((j) + ((j) >= s ? 1 : 0))

// ---- Main: 512 blocks x 256 threads. bid = g*8 + s.
// g = group (16 batch rows), s = unit slice (units [32s, 32s+32)).
__global__ __launch_bounds__(256) void lstm_mfma(
    const int* __restrict__ inp, const uint4* __restrict__ WhB,
    const float4* __restrict__ Wxbg, const float* __restrict__ Wd,
    const float* __restrict__ bd, float* __restrict__ out,
    ull* __restrict__ hx) {
  __shared__ __align__(16) uint4 hfrag[512];     // 8 KB: h_t A-frags (K=256, 16 rows)
  __shared__ float zbuf[16 * ZSB];               // 8.4 KB
  __shared__ float hT[16 * 256];                 // 16 KB (epilogue h_T fp32)
  __shared__ float lgts[16 * 132];               // 8.4 KB
  __shared__ float rmax[16], rsum[16];

  const int tid  = threadIdx.x;
  const int lane = tid & 63;
  const int wv   = tid >> 6;          // 0..3 = wave = pair of col-tiles
  const int bid  = blockIdx.x;
  const int g    = bid >> 3;          // group 0..63
  const int s    = bid & 7;           // unit slice 0..7
  const int r    = tid >> 4;          // 0..15 batch row within group
  const int uis  = tid & 15;          // unit-within-slice (first of pair uis, uis+16)
  const int ubase = s * 32;
  const int NT   = (s >> 2) * 32 + (s & 3) * 8;  // first global col-tile of slice
  const int cq   = lane >> 4, cn = lane & 15;

  // poll-word geometry: word q covers (row rq, local units 2w, 2w+1), w=q&15
  const int q   = tid;
  const int rq  = q >> 4;
  const int up0 = (q & 15) * 2;
  const bool pub = (uis & 1) == 0;    // even-uis threads publish 2 words

  // 7 partner word offsets + A-frag byte addrs
  const int wo0 = SPJ(0) * 256 + q, wo1 = SPJ(1) * 256 + q, wo2 = SPJ(2) * 256 + q,
            wo3 = SPJ(3) * 256 + q, wo4 = SPJ(4) * 256 + q, wo5 = SPJ(5) * 256 + q,
            wo6 = SPJ(6) * 256 + q;
  const int a0 = afrag_addr(SPJ(0) * 32 + up0, rq), a1 = afrag_addr(SPJ(1) * 32 + up0, rq),
            a2 = afrag_addr(SPJ(2) * 32 + up0, rq), a3 = afrag_addr(SPJ(3) * 32 + up0, rq),
            a4 = afrag_addr(SPJ(4) * 32 + up0, rq), a5 = afrag_addr(SPJ(5) * 32 + up0, rq),
            a6 = afrag_addr(SPJ(6) * 32 + up0, rq);
  const int aown0 = afrag_addr(ubase + uis, r);         // u32 pair (uis, uis+1)
  const int aown1 = afrag_addr(ubase + uis + 16, r);    // u32 pair (uis+16, uis+17)
  const int qw    = r * 16 + (uis >> 1);                // publish word (and +8)

  // ---- Weight B-frags: wave wv owns tiles NT+wv*2, NT+wv*2+1, all 8 kk.
  // kk slot 0 = own chunk (kk=s); slots 1..7 = remaining ascending.
  FU wf0[8], wf1[8];
  const int nt0 = NT + wv * 2, nt1 = nt0 + 1;
#pragma unroll
  for (int kx = 0; kx < 8; ++kx) {
    int kk = (kx == 0) ? s : SPJ(kx - 1);
    wf0[kx].u4 = WhB[(nt0 * 8 + kk) * 64 + lane];
    wf1[kx].u4 = WhB[(nt1 * 8 + kk) * 64 + lane];
  }
#pragma unroll
  for (int kx = 0; kx < 8; ++kx) {
    asm volatile("" : "+v"(wf0[kx].u4.x), "+v"(wf0[kx].u4.y), "+v"(wf0[kx].u4.z), "+v"(wf0[kx].u4.w));
    asm volatile("" : "+v"(wf1[kx].u4.x), "+v"(wf1[kx].u4.y), "+v"(wf1[kx].u4.z), "+v"(wf1[kx].u4.w));
  }

  hfrag[tid]       = uint4{0u, 0u, 0u, 0u};   // h_0 = 0
  hfrag[tid + 256] = uint4{0u, 0u, 0u, 0u};
  float cst0 = 0.f, cst1 = 0.f;
  unsigned lastb0 = 0, lastb1 = 0;
  __syncthreads();

  // ---- anti-phase stagger: the co-resident partner (bid+256 <-> groups
  // 32..63 under round-robin placement) starts ~2000cyc late so its
  // compute fills this chain's gather spins (and vice versa). One-time
  // cost ~0.8us; self-timed equal-length chains preserve the offset.
  if (g >= 32) {
#pragma unroll 1
    for (int i = 0; i < 256; ++i) asm volatile("s_nop 7");
  }

  for (int t = 0; t < TSTEPS; ++t) {
    int    ch  = inp[(g * 16 + r) * TSTEPS + t];
    float4 xb0 = Wxbg[ch * 256 + ubase + uis];
    float4 xb1 = Wxbg[ch * 256 + ubase + uis + 16];

    // ---- issue the 7 partner polls early (one overlapped agent RT)
    ull v0 = 0, v1 = 0, v2 = 0, v3 = 0, v4 = 0, v5 = 0, v6 = 0;
    const ull* base = hx + (((t & 1) * 64 + g) << 11);
    if (t > 0) {
      v0 = __hip_atomic_load(base + wo0, __ATOMIC_RELAXED, __HIP_MEMORY_SCOPE_AGENT);
      v1 = __hip_atomic_load(base + wo1, __ATOMIC_RELAXED, __HIP_MEMORY_SCOPE_AGENT);
      v2 = __hip_atomic_load(base + wo2, __ATOMIC_RELAXED, __HIP_MEMORY_SCOPE_AGENT);
      v3 = __hip_atomic_load(base + wo3, __ATOMIC_RELAXED, __HIP_MEMORY_SCOPE_AGENT);
      v4 = __hip_atomic_load(base + wo4, __ATOMIC_RELAXED, __HIP_MEMORY_SCOPE_AGENT);
      v5 = __hip_atomic_load(base + wo5, __ATOMIC_RELAXED, __HIP_MEMORY_SCOPE_AGENT);
      v6 = __hip_atomic_load(base + wo6, __ATOMIC_RELAXED, __HIP_MEMORY_SCOPE_AGENT);
    }

    // ---- own-chunk MFMA (kk = s); t=0: hfrag = 0
    f32x4 acc0 = {0.f, 0.f, 0.f, 0.f}, acc1 = {0.f, 0.f, 0.f, 0.f};
    {
      FU a; a.u4 = hfrag[s * 64 + lane];
      acc0 = __builtin_amdgcn_mfma_f32_16x16x32_f16(a.h8, wf0[0].h8, acc0, 0, 0, 0);
      acc1 = __builtin_amdgcn_mfma_f32_16x16x32_f16(a.h8, wf1[0].h8, acc1, 0, 0, 0);
    }

    if (t > 0) {
      // ---- fused detect+gather: all 7 tags must equal t
      const unsigned tu = (unsigned)t;
      long guard = 0;
      while (((((unsigned)(v0 >> 32)) ^ tu) | (((unsigned)(v1 >> 32)) ^ tu) |
              (((unsigned)(v2 >> 32)) ^ tu) | (((unsigned)(v3 >> 32)) ^ tu) |
              (((unsigned)(v4 >> 32)) ^ tu) | (((unsigned)(v5 >> 32)) ^ tu) |
              (((unsigned)(v6 >> 32)) ^ tu)) != 0u) {
        if (++guard >= (1L << 14)) break;
        v0 = __hip_atomic_load(base + wo0, __ATOMIC_RELAXED, __HIP_MEMORY_SCOPE_AGENT);
        v1 = __hip_atomic_load(base + wo1, __ATOMIC_RELAXED, __HIP_MEMORY_SCOPE_AGENT);
        v2 = __hip_atomic_load(base + wo2, __ATOMIC_RELAXED, __HIP_MEMORY_SCOPE_AGENT);
        v3 = __hip_atomic_load(base + wo3, __ATOMIC_RELAXED, __HIP_MEMORY_SCOPE_AGENT);
        v4 = __hip_atomic_load(base + wo4, __ATOMIC_RELAXED, __HIP_MEMORY_SCOPE_AGENT);
        v5 = __hip_atomic_load(base + wo5, __ATOMIC_RELAXED, __HIP_MEMORY_SCOPE_AGENT);
        v6 = __hip_atomic_load(base + wo6, __ATOMIC_RELAXED, __HIP_MEMORY_SCOPE_AGENT);
      }
      *(unsigned*)((char*)hfrag + a0) = (unsigned)v0;
      *(unsigned*)((char*)hfrag + a1) = (unsigned)v1;
      *(unsigned*)((char*)hfrag + a2) = (unsigned)v2;
      *(unsigned*)((char*)hfrag + a3) = (unsigned)v3;
      *(unsigned*)((char*)hfrag + a4) = (unsigned)v4;
      *(unsigned*)((char*)hfrag + a5) = (unsigned)v5;
      *(unsigned*)((char*)hfrag + a6) = (unsigned)v6;
    }
    __syncthreads();   // hfrag complete; also zbuf handoff barrier

    // ---- remaining 7 K-chunks
#pragma unroll
    for (int kx = 1; kx < 8; ++kx) {
      int kk = SPJ(kx - 1);
      FU a; a.u4 = hfrag[kk * 64 + lane];
      acc0 = __builtin_amdgcn_mfma_f32_16x16x32_f16(a.h8, wf0[kx].h8, acc0, 0, 0, 0);
      acc1 = __builtin_amdgcn_mfma_f32_16x16x32_f16(a.h8, wf1[kx].h8, acc1, 0, 0, 0);
    }
#pragma unroll
    for (int reg = 0; reg < 4; ++reg) {
      zbuf[(cq * 4 + reg) * ZSB + (wv * 2)     * 16 + cn] = acc0[reg];
      zbuf[(cq * 4 + reg) * ZSB + (wv * 2 + 1) * 16 + cn] = acc1[reg];
    }
    __syncthreads();   // zbuf ready

    // ---- gates: thread = (row r, units ubase+uis, ubase+uis+16)
    {
      float4 z0 = *(const float4*)&zbuf[r * ZSB + uis * 4];
      float4 z1 = *(const float4*)&zbuf[r * ZSB + (uis + 16) * 4];
      float i0 = sigm(z0.x + xb0.x), f0 = sigm(z0.y + xb0.y);
      float g0 = tanhx(z0.z + xb0.z), o0 = sigm(z0.w + xb0.w);
      cst0 = f0 * cst0 + i0 * g0;
      float h0 = o0 * tanhx(cst0);
      float i1 = sigm(z1.x + xb1.x), f1 = sigm(z1.y + xb1.y);
      float g1 = tanhx(z1.z + xb1.z), o1 = sigm(z1.w + xb1.w);
      cst1 = f1 * cst1 + i1 * g1;
      float h1 = o1 * tanhx(cst1);

      HP pk; pk.u = 0;
      pk.f[0] = (_Float16)h0; unsigned hb0 = pk.u & 0xffffu;
      pk.u = 0;
      pk.f[0] = (_Float16)h1; unsigned hb1 = pk.u & 0xffffu;
      lastb0 = hb0; lastb1 = hb1;
      unsigned nb0 = (unsigned)__shfl_down((int)hb0, 1, 64);
      unsigned nb1 = (unsigned)__shfl_down((int)hb1, 1, 64);
      if (pub) {
        unsigned pay0 = hb0 | (nb0 << 16);     // units (uis, uis+1)
        unsigned pay1 = hb1 | (nb1 << 16);     // units (uis+16, uis+17)
        *(unsigned*)((char*)hfrag + aown0) = pay0;
        *(unsigned*)((char*)hfrag + aown1) = pay1;
        const ull tag = ((ull)(unsigned)(t + 1)) << 32;
        ull* pbs = hx + ((((t + 1) & 1) * 64 + g) << 11) + s * 256 + qw;
        __hip_atomic_store(pbs,     tag | (ull)pay0, __ATOMIC_RELAXED, __HIP_MEMORY_SCOPE_AGENT);
        __hip_atomic_store(pbs + 8, tag | (ull)pay1, __ATOMIC_RELAXED, __HIP_MEMORY_SCOPE_AGENT);
      }
    }
    __syncthreads();   // own-pair hfrag writes + zbuf handoff
  }

  if (s != 0) return;

  // ---- Epilogue (s==0 blocks, one per group): h_T -> fp32, Wd, softmax.
  // Own slice from the thread's own final fp16 payloads; 7 partner slices
  // polled (tag==TSTEPS, par=0). All h values fp16-rounded (as everywhere).
  {
    HP e0, e1; e0.u = lastb0; e1.u = lastb1;
    hT[r * 256 + uis]      = (float)e0.f[0];
    hT[r * 256 + uis + 16] = (float)e1.f[0];
  }
  {
    const ull* base = hx + ((unsigned)g << 11);  // parity 0
    const unsigned tu = (unsigned)TSTEPS;
    ull v0, v1, v2, v3, v4, v5, v6;
    long guard = 0;
    do {
      v0 = __hip_atomic_load(base + wo0, __ATOMIC_RELAXED, __HIP_MEMORY_SCOPE_AGENT);
      v1 = __hip_atomic_load(base + wo1, __ATOMIC_RELAXED, __HIP_MEMORY_SCOPE_AGENT);
      v2 = __hip_atomic_load(base + wo2, __ATOMIC_RELAXED, __HIP_MEMORY_SCOPE_AGENT);
      v3 = __hip_atomic_load(base + wo3, __ATOMIC_RELAXED, __HIP_MEMORY_SCOPE_AGENT);
      v4 = __hip_atomic_load(base + wo4, __ATOMIC_RELAXED, __HIP_MEMORY_SCOPE_AGENT);
      v5 = __hip_atomic_load(base + wo5, __ATOMIC_RELAXED, __HIP_MEMORY_SCOPE_AGENT);
      v6 = __hip_atomic_load(base + wo6, __ATOMIC_RELAXED, __HIP_MEMORY_SCOPE_AGENT);
    } while (((((unsigned)(v0 >> 32)) ^ tu) | (((unsigned)(v1 >> 32)) ^ tu) |
              (((unsigned)(v2 >> 32)) ^ tu) | (((unsigned)(v3 >> 32)) ^ tu) |
              (((unsigned)(v4 >> 32)) ^ tu) | (((unsigned)(v5 >> 32)) ^ tu) |
              (((unsigned)(v6 >> 32)) ^ tu)) != 0u && ++guard < (1L << 14));
    HP w;
    w.u = (unsigned)v0; hT[rq * 256 + SPJ(0) * 32 + up0] = (float)w.f[0];
                        hT[rq * 256 + SPJ(0) * 32 + up0 + 1] = (float)w.f[1];
    w.u = (unsigned)v1; hT[rq * 256 + SPJ(1) * 32 + up0] = (float)w.f[0];
                        hT[rq * 256 + SPJ(1) * 32 + up0 + 1] = (float)w.f[1];
    w.u = (unsigned)v2; hT[rq * 256 + SPJ(2) * 32 + up0] = (float)w.f[0];
                        hT[rq * 256 + SPJ(2) * 32 + up0 + 1] = (float)w.f[1];
    w.u = (unsigned)v3; hT[rq * 256 + SPJ(3) * 32 + up0] = (float)w.f[0];
                        hT[rq * 256 + SPJ(3) * 32 + up0 + 1] = (float)w.f[1];
    w.u = (unsigned)v4; hT[rq * 256 + SPJ(4) * 32 + up0] = (float)w.f[0];
                        hT[rq * 256 + SPJ(4) * 32 + up0 + 1] = (float)w.f[1];
    w.u = (unsigned)v5; hT[rq * 256 + SPJ(5) * 32 + up0] = (float)w.f[0];
                        hT[rq * 256 + SPJ(5) * 32 + up0 + 1] = (float)w.f[1];
    w.u = (unsigned)v6; hT[rq * 256 + SPJ(6) * 32 + up0] = (float)w.f[0];
                        hT[rq * 256 + SPJ(6) * 32 + up0 + 1] = (float)w.f[1];
  }
  __syncthreads();
  {
    const int j  = tid & 127;
    const int rb = tid >> 7;            // 0..1 -> rows rb*8 .. rb*8+7
    float l[8];
#pragma unroll
    for (int i = 0; i < 8; ++i) l[i] = bd[j];
    for (int k = 0; k < 256; ++k) {
      float w = Wd[k * NCHAR + j];
#pragma unroll
      for (int i = 0; i < 8; ++i)
        l[i] += hT[(rb * 8 + i) * 256 + k] * w;
    }
#pragma unroll
    for (int i = 0; i < 8; ++i)
      lgts[(rb * 8 + i) * 132 + j] = l[i];
  }
  __syncthreads();
  if (tid < 16) {
    const int rr = tid;
    float m = -1e30f;
    for (int j = 0; j < NCHAR; ++j) m = fmaxf(m, lgts[rr * 132 + j]);
    float sum = 0.f;
    for (int j = 0; j < NCHAR; ++j) sum += __expf(lgts[rr * 132 + j] - m);
    rmax[rr] = m;
    rsum[rr] = fast_rcp(sum);
  }
  __syncthreads();
  {
    const int j  = tid & 127;
    const int rb = tid >> 7;
#pragma unroll
    for (int i = 0; i < 8; ++i) {
      int rr = rb * 8 + i;
      out[(g * 16 + rr) * NCHAR + j] = __expf(lgts[rr * 132 + j] - rmax[rr]) * rsum[rr];
    }
  }
}

extern "C" void kernel_launch(void* const* d_in, const int* in_sizes, int n_in,
                              void* d_out, int out_size, void* d_ws, size_t ws_size,
                              hipStream_t stream) {
  const int*   inp = (const int*)d_in[0];
  const float* Wx  = (const float*)d_in[1];
  const float* Wh  = (const float*)d_in[2];
  const float* bia = (const float*)d_in[3];
  const float* Wd  = (const float*)d_in[4];
  const float* bd  = (const float*)d_in[5];

  uint4*  WhB  = (uint4*)d_ws;                          // 512 KB
  float4* Wxbg = (float4*)((char*)d_ws + (512 << 10));  // 512 KB
  ull*    hx   = (ull*)((char*)d_ws + (1 << 20));       // 2 MB

  prep_whB<<<128, 256, 0, stream>>>(Wh, WhB);
  prep_wx<<<128, 256, 0, stream>>>(Wx, bia, Wxbg);
  lstm_mfma<<<512, 256, 0, stream>>>(inp, WhB, Wxbg, Wd, bd, (float*)d_out, hx);
}

// Round 6
// 968.551 us; speedup vs baseline: 2.0329x; 1.1987x over previous
//
#include <hip/hip_runtime.h>

// LSTM char-RNN forward: batch=1024, T=512, UNITS=256, NUM_CHARS=128.
// R14: in-register gates via gate-major B-layout. 256 blocks x 256 threads
// (g = bid&63 group of 16 rows, c = bid>>6 unit quarter of 64 units),
// 4 waves/block, 1 block/CU.
//
// Why: R12 (software 2-phase) and R13 (8-way co-residency) both regressed
// by INCREASING exchange consumers/traffic (R13: FETCH 268MB->1.85GB,
// 2.1TB/s on the fabric). R14 keeps R11's proven 4-way/3-consumer exchange
// and instead deletes structural overhead: wave wv owns the 4 gate-tiles
// (i,f,g,o) of unit-block c*4+wv, so after MFMA each lane holds all 4
// gates of (4 rows x 1 unit) IN REGISTERS. Gates compute in-lane; c-state
// stays in the acc-holder lane. This removes: zbuf write+read (the 5.0e7
// bank conflicts), one of three barriers, the gates' LDS latency, and the
// __shfl payload pairing (row-pairs are in-lane). inp is staged in LDS
// once (no per-step global ch load). Polls are 2-deep pipelined (set A
// before own-chunk MFMAs, set B between, per-word selective re-poll) to
// cut the agent-RT quantization. Exchange keeps the proven u64
// (tag32|2xfp16) parity-double-buffered agent-scope scheme
// (stale/poison/replay-proof via tag==t equality; replay-safe because
// payloads are deterministic). h is fp16-rounded everywhere as before.

#define TSTEPS 512
#define UNITS  256
#define NCHAR  128
#define G4     1024
#define ISTR   20    // inp_lds row stride (ints): 8-way-spread banks, 16B-aligned reads

typedef float    f32x4 __attribute__((ext_vector_type(4)));
typedef _Float16 f16x8 __attribute__((ext_vector_type(8)));
typedef unsigned long long ull;

union FU { uint4 u4; f16x8 h8; _Float16 h[8]; };
union HP { unsigned int u; _Float16 f[2]; };

__device__ __forceinline__ float fast_rcp(float x) {
#if __has_builtin(__builtin_amdgcn_rcpf)
  return __builtin_amdgcn_rcpf(x);
#else
  return 1.0f / x;
#endif
}
__device__ __forceinline__ float sigm(float x)  { return fast_rcp(1.0f + __expf(-x)); }
__device__ __forceinline__ float tanhx(float x) { return 2.0f * fast_rcp(1.0f + __expf(-2.0f * x)) - 1.0f; }

__device__ __forceinline__ ull ld_agent(const ull* p) {
  return __hip_atomic_load(p, __ATOMIC_RELAXED, __HIP_MEMORY_SCOPE_AGENT);
}
__device__ __forceinline__ void st_agent(ull* p, ull v) {
  __hip_atomic_store(p, v, __ATOMIC_RELAXED, __HIP_MEMORY_SCOPE_AGENT);
}

// ---- Prep: gate-major B-frags. WhB[((ub*4+gate)*8+kk)*64 + l].
// Tile (ub, gate): col = gate*256 + ub*16 + (l&15); k = kk*32 + (l>>4)*8 + j.
__global__ void prep_whB(const float* __restrict__ Wh, uint4* __restrict__ WhB) {
  int idx = blockIdx.x * blockDim.x + threadIdx.x;    // 0..32767
  int l    = idx & 63;
  int kk   = (idx >> 6) & 7;
  int gate = (idx >> 9) & 3;
  int ub   = idx >> 11;                               // 0..15
  int col  = gate * 256 + ub * 16 + (l & 15);
  int kb   = kk * 32 + (l >> 4) * 8;
  FU p;
#pragma unroll
  for (int j = 0; j < 8; ++j)
    p.h[j] = (_Float16)Wh[(kb + j) * G4 + col];
  WhB[idx] = p.u4;
}

// ---- Prep: Wxbg[ch][u] = float4(i,f,g,o) = Wx[ch][gate*256+u] + b
__global__ void prep_wx(const float* __restrict__ Wx, const float* __restrict__ bias,
                        float4* __restrict__ Wxbg) {
  int idx = blockIdx.x * blockDim.x + threadIdx.x;    // 0..32767
  int u  = idx & (UNITS - 1);
  int ch = idx >> 8;
  const float* r = Wx + ch * G4;
  float4 o;
  o.x = r[0 * UNITS + u] + bias[0 * UNITS + u];
  o.y = r[1 * UNITS + u] + bias[1 * UNITS + u];
  o.z = r[2 * UNITS + u] + bias[2 * UNITS + u];
  o.w = r[3 * UNITS + u] + bias[3 * UNITS + u];
  Wxbg[idx] = o;
}

// A-frag LDS byte address for h element (row m, k). Proven layout (R8/R11).
__device__ __forceinline__ int afrag_addr(int k, int m) {
  return ((k >> 5) << 10) + (((((k >> 3) & 3) << 4) + m) << 4) + ((k & 7) << 1);
}

#define MFMA16(a, b, c_) __builtin_amdgcn_mfma_f32_16x16x32_f16(a, b, c_, 0, 0, 0)

// ---- Main: 256 blocks x 256 threads. g = bid&63, c = bid>>6.
__global__ __launch_bounds__(256, 1) void lstm_mfma(
    const int* __restrict__ inp, const uint4* __restrict__ WhB,
    const float4* __restrict__ Wxbg, const float* __restrict__ Wd,
    const float* __restrict__ bd, float* __restrict__ out,
    ull* __restrict__ hx) {
  __shared__ __align__(16) uint4 hfrag[512];            // 8 KB: h_t A-frags
  __shared__ __align__(16) int   inp_lds[TSTEPS * ISTR]; // 40 KB; epilogue hT overlay
  __shared__ float lgts[16 * 132];                      // 8.4 KB
  __shared__ float rmax[16], rsum[16];

  const int tid  = threadIdx.x;
  const int lane = tid & 63;
  const int wv   = tid >> 6;          // 0..3: wave = unit-block c*4+wv
  const int g    = blockIdx.x & 63;
  const int c    = blockIdx.x >> 6;   // unit quarter 0..3
  const int cq   = lane >> 4, cn = lane & 15;
  const int u    = c * 64 + wv * 16 + cn;   // this lane's unit

  const int cpa = (c == 0) ? 1 : 0;
  const int cpb = (c <= 1) ? 2 : 1;
  const int cpc = (c <= 2) ? 3 : 2;

  // ---- Weight B-frags: 4 gates x 8 kk for unit-block c*4+wv.
  // kk slot order: 0,1 = own K-chunk (kk = 2c, 2c+1); 2..7 = rest ascending.
  FU wf[4][8];
#pragma unroll
  for (int gt = 0; gt < 4; ++gt)
#pragma unroll
    for (int kx = 0; kx < 8; ++kx) {
      int i2 = kx - 2;
      int kk = (kx < 2) ? (2 * c + kx) : (i2 + ((i2 >= 2 * c) ? 2 : 0));
      wf[gt][kx].u4 = WhB[(((c * 4 + wv) * 4 + gt) * 8 + kk) * 64 + lane];
    }
#pragma unroll
  for (int gt = 0; gt < 4; ++gt)
#pragma unroll
    for (int kx = 0; kx < 8; ++kx)
      asm volatile("" : "+v"(wf[gt][kx].u4.x), "+v"(wf[gt][kx].u4.y),
                        "+v"(wf[gt][kx].u4.z), "+v"(wf[gt][kx].u4.w));

  // ---- inp staging: inp_lds[t*ISTR + row] (coalesced global reads)
#pragma unroll 1
  for (int i = 0; i < 32; ++i) {
    int e = i * 256 + tid;            // 0..8191
    int row = e >> 9, tt = e & 511;
    inp_lds[tt * ISTR + row] = inp[(g * 16 + row) * TSTEPS + tt];
  }
  hfrag[tid]       = uint4{0u, 0u, 0u, 0u};   // h_0 = 0
  hfrag[tid + 256] = uint4{0u, 0u, 0u, 0u};

  // ---- gather geometry: thread owns words w=tid (rpA) and w=tid+256 (rpB)
  const int ulA = tid & 63, rpA = tid >> 6, rpB = rpA + 4;
  int ga[12];
  {
    int k0 = cpa * 64 + ulA;
    ga[0] = afrag_addr(k0, 2 * rpA); ga[1] = afrag_addr(k0, 2 * rpA + 1);
    ga[2] = afrag_addr(k0, 2 * rpB); ga[3] = afrag_addr(k0, 2 * rpB + 1);
    int k1 = cpb * 64 + ulA;
    ga[4] = afrag_addr(k1, 2 * rpA); ga[5] = afrag_addr(k1, 2 * rpA + 1);
    ga[6] = afrag_addr(k1, 2 * rpB); ga[7] = afrag_addr(k1, 2 * rpB + 1);
    int k2 = cpc * 64 + ulA;
    ga[8] = afrag_addr(k2, 2 * rpA); ga[9] = afrag_addr(k2, 2 * rpA + 1);
    ga[10] = afrag_addr(k2, 2 * rpB); ga[11] = afrag_addr(k2, 2 * rpB + 1);
  }
  const int aown0 = afrag_addr(u, 4 * cq + 0);
  const int aown1 = afrag_addr(u, 4 * cq + 1);
  const int aown2 = afrag_addr(u, 4 * cq + 2);
  const int aown3 = afrag_addr(u, 4 * cq + 3);
  const int w0 = (2 * cq) * 64 + (wv * 16 + cn), w1 = w0 + 64;

  float cst[4]   = {0.f, 0.f, 0.f, 0.f};
  float lasth[4] = {0.f, 0.f, 0.f, 0.f};
  __syncthreads();

  for (int t = 0; t < TSTEPS; ++t) {
    int4 chv = *(const int4*)&inp_lds[t * ISTR + 4 * cq];
    float4 xbv[4];
    xbv[0] = Wxbg[chv.x * 256 + u];
    xbv[1] = Wxbg[chv.y * 256 + u];
    xbv[2] = Wxbg[chv.z * 256 + u];
    xbv[3] = Wxbg[chv.w * 256 + u];

    // ---- poll set A (issued before own-chunk MFMAs)
    ull a0 = 0, a1 = 0, a2 = 0, a3 = 0, a4 = 0, a5 = 0;
    ull b0 = 0, b1 = 0, b2 = 0, b3 = 0, b4 = 0, b5 = 0;
    const ull* sb = hx + ((ull)(t & 1) << 17) + (g << 11);
    const ull* pa = sb + (cpa << 9) + tid;
    const ull* pb = sb + (cpb << 9) + tid;
    const ull* pc = sb + (cpc << 9) + tid;
    if (t > 0) {
      a0 = ld_agent(pa); a1 = ld_agent(pa + 256);
      a2 = ld_agent(pb); a3 = ld_agent(pb + 256);
      a4 = ld_agent(pc); a5 = ld_agent(pc + 256);
    }
    __builtin_amdgcn_sched_barrier(0);

    f32x4 acc0 = {0.f,0.f,0.f,0.f}, acc1 = {0.f,0.f,0.f,0.f},
          acc2 = {0.f,0.f,0.f,0.f}, acc3 = {0.f,0.f,0.f,0.f};
    {   // own chunk kk = 2c
      FU a; a.u4 = hfrag[(2 * c) * 64 + lane];
      acc0 = MFMA16(a.h8, wf[0][0].h8, acc0);
      acc1 = MFMA16(a.h8, wf[1][0].h8, acc1);
      acc2 = MFMA16(a.h8, wf[2][0].h8, acc2);
      acc3 = MFMA16(a.h8, wf[3][0].h8, acc3);
    }
    __builtin_amdgcn_sched_barrier(0);
    if (t > 0) {   // poll set B (staggered ~half an RT later)
      b0 = ld_agent(pa); b1 = ld_agent(pa + 256);
      b2 = ld_agent(pb); b3 = ld_agent(pb + 256);
      b4 = ld_agent(pc); b5 = ld_agent(pc + 256);
    }
    __builtin_amdgcn_sched_barrier(0);
    {   // own chunk kk = 2c+1
      FU a; a.u4 = hfrag[(2 * c + 1) * 64 + lane];
      acc0 = MFMA16(a.h8, wf[0][1].h8, acc0);
      acc1 = MFMA16(a.h8, wf[1][1].h8, acc1);
      acc2 = MFMA16(a.h8, wf[2][1].h8, acc2);
      acc3 = MFMA16(a.h8, wf[3][1].h8, acc3);
    }

    if (t > 0) {
      // ---- fused detect+gather: per-word A-or-B select, selective re-poll
      const unsigned tu = (unsigned)t;
      ull v0 = ((unsigned)(a0 >> 32) == tu) ? a0 : b0;
      ull v1 = ((unsigned)(a1 >> 32) == tu) ? a1 : b1;
      ull v2 = ((unsigned)(a2 >> 32) == tu) ? a2 : b2;
      ull v3 = ((unsigned)(a3 >> 32) == tu) ? a3 : b3;
      ull v4 = ((unsigned)(a4 >> 32) == tu) ? a4 : b4;
      ull v5 = ((unsigned)(a5 >> 32) == tu) ? a5 : b5;
      long guard = 0;
      while (((((unsigned)(v0 >> 32)) ^ tu) | (((unsigned)(v1 >> 32)) ^ tu) |
              (((unsigned)(v2 >> 32)) ^ tu) | (((unsigned)(v3 >> 32)) ^ tu) |
              (((unsigned)(v4 >> 32)) ^ tu) | (((unsigned)(v5 >> 32)) ^ tu)) != 0u
             && ++guard < (1L << 14)) {
        if ((unsigned)(v0 >> 32) != tu) v0 = ld_agent(pa);
        if ((unsigned)(v1 >> 32) != tu) v1 = ld_agent(pa + 256);
        if ((unsigned)(v2 >> 32) != tu) v2 = ld_agent(pb);
        if ((unsigned)(v3 >> 32) != tu) v3 = ld_agent(pb + 256);
        if ((unsigned)(v4 >> 32) != tu) v4 = ld_agent(pc);
        if ((unsigned)(v5 >> 32) != tu) v5 = ld_agent(pc + 256);
      }
      char* hb = (char*)hfrag;
      *(unsigned short*)(hb + ga[0])  = (unsigned short)v0;
      *(unsigned short*)(hb + ga[1])  = (unsigned short)(v0 >> 16);
      *(unsigned short*)(hb + ga[2])  = (unsigned short)v1;
      *(unsigned short*)(hb + ga[3])  = (unsigned short)(v1 >> 16);
      *(unsigned short*)(hb + ga[4])  = (unsigned short)v2;
      *(unsigned short*)(hb + ga[5])  = (unsigned short)(v2 >> 16);
      *(unsigned short*)(hb + ga[6])  = (unsigned short)v3;
      *(unsigned short*)(hb + ga[7])  = (unsigned short)(v3 >> 16);
      *(unsigned short*)(hb + ga[8])  = (unsigned short)v4;
      *(unsigned short*)(hb + ga[9])  = (unsigned short)(v4 >> 16);
      *(unsigned short*)(hb + ga[10]) = (unsigned short)v5;
      *(unsigned short*)(hb + ga[11]) = (unsigned short)(v5 >> 16);
    }
    __syncthreads();   // B1: gather complete

    // ---- partner K-chunks
#pragma unroll
    for (int kx = 2; kx < 8; ++kx) {
      int i2 = kx - 2;
      int kk = i2 + ((i2 >= 2 * c) ? 2 : 0);
      FU a; a.u4 = hfrag[kk * 64 + lane];
      acc0 = MFMA16(a.h8, wf[0][kx].h8, acc0);
      acc1 = MFMA16(a.h8, wf[1][kx].h8, acc1);
      acc2 = MFMA16(a.h8, wf[2][kx].h8, acc2);
      acc3 = MFMA16(a.h8, wf[3][kx].h8, acc3);
    }

    // ---- in-register gates: lane = (4 rows 4cq+rg, unit u)
    unsigned hb16[4];
#pragma unroll
    for (int rg = 0; rg < 4; ++rg) {
      float zi = acc0[rg] + xbv[rg].x;
      float zf = acc1[rg] + xbv[rg].y;
      float zg = acc2[rg] + xbv[rg].z;
      float zo = acc3[rg] + xbv[rg].w;
      float ii = sigm(zi), ff = sigm(zf);
      float gg = tanhx(zg), oo = sigm(zo);
      cst[rg] = ff * cst[rg] + ii * gg;
      float h = oo * tanhx(cst[rg]);
      HP hp; hp.u = 0; hp.f[0] = (_Float16)h;
      hb16[rg]  = hp.u & 0xffffu;
      lasth[rg] = (float)hp.f[0];
    }
    {
      char* hb = (char*)hfrag;   // own A-frag slots (own chunk kk = 2c,2c+1)
      *(unsigned short*)(hb + aown0) = (unsigned short)hb16[0];
      *(unsigned short*)(hb + aown1) = (unsigned short)hb16[1];
      *(unsigned short*)(hb + aown2) = (unsigned short)hb16[2];
      *(unsigned short*)(hb + aown3) = (unsigned short)hb16[3];
      // publish: rows are in-lane -> row-pair payloads, no shfl
      const ull tag = ((ull)(unsigned)(t + 1)) << 32;
      ull* db = hx + ((ull)((t + 1) & 1) << 17) + (g << 11) + (c << 9);
      st_agent(db + w0, tag | (ull)(hb16[0] | (hb16[1] << 16)));
      st_agent(db + w1, tag | (ull)(hb16[2] | (hb16[3] << 16)));
    }
    __syncthreads();   // B2: own-writes visible for next own-chunk MFMA
  }

  if (c != 0) return;

  // ---- Epilogue (c==0 blocks): h_T -> fp32 (overlay inp_lds), Wd, softmax.
  float* hT = (float*)inp_lds;   // 16x256 fp32 = 16KB <= 40KB
#pragma unroll
  for (int rg = 0; rg < 4; ++rg) hT[(4 * cq + rg) * 256 + u] = lasth[rg];
  {
    const ull* sb = hx + (g << 11);   // parity 0 (tag TSTEPS)
    const ull* pa = sb + (cpa << 9) + tid;
    const ull* pb = sb + (cpb << 9) + tid;
    const ull* pc = sb + (cpc << 9) + tid;
    const unsigned tu = (unsigned)TSTEPS;
    ull v0, v1, v2, v3, v4, v5;
    long guard = 0;
    do {
      v0 = ld_agent(pa); v1 = ld_agent(pa + 256);
      v2 = ld_agent(pb); v3 = ld_agent(pb + 256);
      v4 = ld_agent(pc); v5 = ld_agent(pc + 256);
    } while (((((unsigned)(v0 >> 32)) ^ tu) | (((unsigned)(v1 >> 32)) ^ tu) |
              (((unsigned)(v2 >> 32)) ^ tu) | (((unsigned)(v3 >> 32)) ^ tu) |
              (((unsigned)(v4 >> 32)) ^ tu) | (((unsigned)(v5 >> 32)) ^ tu)) != 0u
             && ++guard < (1L << 14));
    HP w;
    w.u = (unsigned)v0; hT[(2 * rpA) * 256 + cpa * 64 + ulA]     = (float)w.f[0];
                        hT[(2 * rpA + 1) * 256 + cpa * 64 + ulA] = (float)w.f[1];
    w.u = (unsigned)v1; hT[(2 * rpB) * 256 + cpa * 64 + ulA]     = (float)w.f[0];
                        hT[(2 * rpB + 1) * 256 + cpa * 64 + ulA] = (float)w.f[1];
    w.u = (unsigned)v2; hT[(2 * rpA) * 256 + cpb * 64 + ulA]     = (float)w.f[0];
                        hT[(2 * rpA + 1) * 256 + cpb * 64 + ulA] = (float)w.f[1];
    w.u = (unsigned)v3; hT[(2 * rpB) * 256 + cpb * 64 + ulA]     = (float)w.f[0];
                        hT[(2 * rpB + 1) * 256 + cpb * 64 + ulA] = (float)w.f[1];
    w.u = (unsigned)v4; hT[(2 * rpA) * 256 + cpc * 64 + ulA]     = (float)w.f[0];
                        hT[(2 * rpA + 1) * 256 + cpc * 64 + ulA] = (float)w.f[1];
    w.u = (unsigned)v5; hT[(2 * rpB) * 256 + cpc * 64 + ulA]     = (float)w.f[0];
                        hT[(2 * rpB + 1) * 256 + cpc * 64 + ulA] = (float)w.f[1];
  }
  __syncthreads();
  {
    const int j = tid & 127, rh = tid >> 7;    // rows rh*8 .. rh*8+7
    float l[8];
#pragma unroll
    for (int i = 0; i < 8; ++i) l[i] = bd[j];
    for (int k = 0; k < 256; ++k) {
      float w = Wd[k * NCHAR + j];
#pragma unroll
      for (int i = 0; i < 8; ++i) l[i] += hT[(rh * 8 + i) * 256 + k] * w;
    }
#pragma unroll
    for (int i = 0; i < 8; ++i) lgts[(rh * 8 + i) * 132 + j] = l[i];
  }
  __syncthreads();
  if (tid < 16) {
    const int rr = tid;
    float m = -1e30f;
    for (int j = 0; j < NCHAR; ++j) m = fmaxf(m, lgts[rr * 132 + j]);
    float s = 0.f;
    for (int j = 0; j < NCHAR; ++j) s += __expf(lgts[rr * 132 + j] - m);
    rmax[rr] = m;
    rsum[rr] = fast_rcp(s);
  }
  __syncthreads();
  {
    const int j = tid & 127, rh = tid >> 7;
#pragma unroll
    for (int i = 0; i < 8; ++i) {
      int rr = rh * 8 + i;
      out[(g * 16 + rr) * NCHAR + j] = __expf(lgts[rr * 132 + j] - rmax[rr]) * rsum[rr];
    }
  }
}

extern "C" void kernel_launch(void* const* d_in, const int* in_sizes, int n_in,
                              void* d_out, int out_size, void* d_ws, size_t ws_size,
                              hipStream_t stream) {
  const int*   inp = (const int*)d_in[0];
  const float* Wx  = (const float*)d_in[1];
  const float* Wh  = (const float*)d_in[2];
  const float* bia = (const float*)d_in[3];
  const float* Wd  = (const float*)d_in[4];
  const float* bd  = (const float*)d_in[5];

  uint4*  WhB  = (uint4*)d_ws;                          // 512 KB
  float4* Wxbg = (float4*)((char*)d_ws + (512 << 10));  // 512 KB
  ull*    hx   = (ull*)((char*)d_ws + (1 << 20));       // 2 MB

  prep_whB<<<128, 256, 0, stream>>>(Wh, WhB);
  prep_wx<<<128, 256, 0, stream>>>(Wx, bia, Wxbg);
  lstm_mfma<<<256, 256, 0, stream>>>(inp, WhB, Wxbg, Wd, bd, (float*)d_out, hx);
}